// Round 8
// baseline (158.531 us; speedup 1.0000x reference)
//
#include <hip/hip_runtime.h>
#include <hip/hip_bf16.h>

#define NA    90000
#define NGT   256
#define KNMS  2000
#define RPAD  2048          // padded NMS rows (multiple of 64)
#define NBINS 4096
#define CMAX  4096          // compact buffer capacity
#define IMGSZ 1600.0f

// ---------------- ws layout (bytes) ----------------
// keys  : 0        .. 720000   (u64[90000])
// hist  : 720000   .. 736384   (u32[4096])     } aliased: hist dead after k_compact,
// diagw : 720000   .. 736384   (u64[2048])     } diagw written later by k_mask
// ctr   : 736384   .. 736400   (u32[4])   [0]=compact count
// buf   : 736400   .. 769168   (u64[4096])
// cand  : 769168   .. 801936   (float4[2048])
// maskT : 801936   .. 1326224  (u32[64][2048]  transposed: word-plane major)

__device__ __forceinline__ float4 compute_local(int k) {
    const float ratios[3] = {0.5f, 1.0f, 2.0f};
    const float scales[3] = {8.0f, 16.0f, 32.0f};
    int r = k / 3, sc = k % 3;
    float b0 = 0.0f, b1 = 0.0f, b2 = 15.0f, b3 = 15.0f;
    float y0 = b0 + 0.5f * (b3 - 1.0f);
    float y1 = b1 + 0.5f * (b2 - 1.0f);
    float y2 = b3 - b1 + 1.0f;
    float y3 = b2 - b0 + 1.0f;
    float wr = rintf(sqrtf(y2 * y3 / ratios[r]));   // jnp.round = half-even = rintf
    float hr = rintf(wr * ratios[r]);
    float a0 = y0 - 0.5f * (wr - 1.0f);
    float a1 = y1 - 0.5f * (hr - 1.0f);
    float a2 = y0 + 0.5f * (wr - 1.0f);
    float a3 = y1 + 0.5f * (hr - 1.0f);
    float ya0 = a0 + 0.5f * (a3 - 1.0f);
    float ya1 = a1 + 0.5f * (a2 - 1.0f);
    float ya2 = a3 - a1 + 1.0f;
    float ya3 = a2 - a0 + 1.0f;
    float w = ya2 * scales[sc];
    float h = ya3 * scales[sc];
    float4 o;
    o.x = ya0 - 0.5f * (w - 1.0f);
    o.y = ya1 - 0.5f * (h - 1.0f);
    o.z = ya0 + 0.5f * (w - 1.0f);
    o.w = ya1 + 0.5f * (h - 1.0f);
    return o;
}

__global__ void k_zero(unsigned int* __restrict__ hist, unsigned int* __restrict__ ctr) {
    int i = blockIdx.x * 256 + threadIdx.x;
    if (i < NBINS) hist[i] = 0u;
    if (i < 4) ctr[i] = 0u;
}

__global__ __launch_bounds__(256) void k_prep(
    const float* __restrict__ true_bx, const float* __restrict__ deltas,
    const float* __restrict__ scores, float* __restrict__ out,
    unsigned long long* __restrict__ keys, unsigned int* __restrict__ hist)
{
    __shared__ float4 gt[NGT];
    int tid = threadIdx.x;
    for (int i = tid; i < NGT; i += 256) gt[i] = ((const float4*)true_bx)[i];
    __syncthreads();

    int a = blockIdx.x * 256 + tid;
    if (a >= NA) return;

    int k  = a % 9;
    int s  = a / 9;
    int ix = s % 100;
    int iy = s / 100;

    float4 loc = compute_local(k);
    float sxv = (float)ix * 16.0f, syv = (float)iy * 16.0f;
    float ax1 = fminf(fmaxf(loc.x + sxv, 0.0f), IMGSZ);
    float ay1 = fminf(fmaxf(loc.y + syv, 0.0f), IMGSZ);
    float ax2 = fminf(fmaxf(loc.z + sxv, 0.0f), IMGSZ);
    float ay2 = fminf(fmaxf(loc.w + syv, 0.0f), IMGSZ);
    float areaA = (ax2 - ax1) * (ay2 - ay1);

    // argmax over 256 GTs, strict > keeps FIRST max (jnp.argmax semantics)
    float best = -1.0f; int bidx = 0;
    #pragma unroll 4
    for (int g = 0; g < NGT; ++g) {
        float4 G = gt[g];
        float areaG = (G.z - G.x) * (G.w - G.y);
        float lx = fmaxf(G.x, ax1), ly = fmaxf(G.y, ay1);
        float rx = fminf(G.z, ax2), ry = fminf(G.w, ay2);
        float iw = fmaxf(rx - lx, 0.0f), ih = fmaxf(ry - ly, 0.0f);
        float inter = iw * ih;
        float iou = inter / (areaG + areaA - inter);
        if (iou > best) { best = iou; bidx = g; }
    }

    float4 G = gt[bidx];
    float scx = (ax1 + ax2) * 0.5f, scy = (ay1 + ay2) * 0.5f;
    float sw = ax2 - ax1, sh = ay2 - ay1;
    float dcx = (G.x + G.z) * 0.5f, dcy = (G.y + G.w) * 0.5f;
    float dw = G.z - G.x, dh = G.w - G.y;
    float t0 = (scx - dcx) / dw;
    float t1 = (scy - dcy) / dh;
    float t2 = logf(sw / dw);
    float t3 = logf(sh / dh);

    float4 d = ((const float4*)deltas)[a];
    float cx = d.x * sw + scx, cy = d.y * sh + scy;
    float w = expf(d.z) * sw, h = expf(d.w) * sh;
    float r0 = fminf(fmaxf(cx - 0.5f * w, 0.0f), IMGSZ);
    float r1 = fminf(fmaxf(cy - 0.5f * h, 0.0f), IMGSZ);
    float r2 = fminf(fmaxf(cx + 0.5f * w, 0.0f), IMGSZ);
    float r3 = fminf(fmaxf(cy + 0.5f * h, 0.0f), IMGSZ);

    float* row = out + (size_t)a * 9;
    row[0] = t0; row[1] = t1; row[2] = t2; row[3] = t3;
    row[4] = r0; row[5] = r1; row[6] = r2; row[7] = r3;
    row[8] = best;

    float sc = scores[a];
    unsigned int b = __float_as_uint(sc);
    unsigned int m = (b & 0x80000000u) ? ~b : (b | 0x80000000u);  // monotone map
    keys[a] = ((unsigned long long)m << 32) | (unsigned long long)(0xFFFFFFFFu - (unsigned int)a);
    int bin = (int)(sc * (float)NBINS);
    bin = bin < 0 ? 0 : (bin > NBINS - 1 ? NBINS - 1 : bin);
    atomicAdd(&hist[bin], 1u);
}

// compact with inlined threshold-bin scan (wave 0 of each block recomputes B;
// scores are uniform so the scan terminates in ~2 chunk iterations, L2-resident)
__global__ __launch_bounds__(256) void k_compact(
    const float* __restrict__ scores, const unsigned long long* __restrict__ keys,
    const unsigned int* __restrict__ hist, unsigned int* __restrict__ ctr,
    unsigned long long* __restrict__ buf)
{
    __shared__ unsigned int Bsh;
    int tid = threadIdx.x;
    if (tid < 64) {
        int lane = tid;
        unsigned int cum = 0; unsigned int Bv = 0u; bool found = false;
        for (int c = 0; c < 64 && !found; ++c) {
            int bin = NBINS - 1 - c * 64 - lane;
            unsigned int s = hist[bin];
            #pragma unroll
            for (int d = 1; d < 64; d <<= 1) {
                unsigned int t = __shfl_up(s, d, 64);
                if (lane >= d) s += t;
            }
            unsigned long long ball = __ballot(cum + s >= (unsigned int)KNMS);
            if (ball) {
                found = true;
                Bv = (unsigned int)(NBINS - 1 - c * 64 - __builtin_ctzll(ball));
            }
            cum += __shfl(s, 63, 64);
        }
        if (tid == 0) Bsh = found ? Bv : 0u;
    }
    __syncthreads();
    unsigned int B = Bsh;

    int a = blockIdx.x * 256 + tid;
    if (a >= NA) return;
    float sc = scores[a];
    int bin = (int)(sc * (float)NBINS);
    bin = bin < 0 ? 0 : (bin > NBINS - 1 ? NBINS - 1 : bin);
    if ((unsigned int)bin >= B) {
        unsigned int p = atomicAdd(&ctr[0], 1u);
        if (p < CMAX) buf[p] = keys[a];
    }
}

// Enumeration (rank) scatter: keys unique -> sorted position = #{keys > mine}.
__global__ __launch_bounds__(256) void k_rank(
    const unsigned int* __restrict__ ctr, const unsigned long long* __restrict__ buf,
    const float* __restrict__ out, float4* __restrict__ cand)
{
    __shared__ unsigned long long S[CMAX];
    const int tid = threadIdx.x;
    unsigned int M = ctr[0];
    if (M > (unsigned int)CMAX) M = CMAX;
    for (int i = tid; i < CMAX; i += 256) S[i] = (i < (int)M) ? buf[i] : 0ull;
    __syncthreads();

    const int me = blockIdx.x * 256 + tid;          // candidate slot
    const unsigned long long my = (me < (int)M) ? S[me] : 0ull;
    const int M4 = ((int)M + 3) & ~3;               // pad entries are 0, never > a real key
    int r0 = 0, r1 = 0;
    for (int i = 0; i < M4; i += 4) {
        unsigned long long k0 = S[i], k1 = S[i + 1], k2 = S[i + 2], k3 = S[i + 3];
        r0 += (k0 > my); r1 += (k1 > my);
        r0 += (k2 > my); r1 += (k3 > my);
    }
    const int rank = r0 + r1;
    if (me < (int)M && rank < KNMS) {
        unsigned int idx = 0xFFFFFFFFu - (unsigned int)(my & 0xFFFFFFFFull);
        const float* row = out + (size_t)idx * 9;
        cand[rank] = make_float4(row[4], row[5], row[6], row[7]);
    }
}

__global__ __launch_bounds__(64) void k_mask(
    const float4* __restrict__ cand, unsigned int* __restrict__ maskT,
    unsigned long long* __restrict__ diagw)
{
    int rowChunk = blockIdx.x;   // 0..31
    int colChunk = blockIdx.y;   // 0..31
    __shared__ float4 cb[64];
    int t = threadIdx.x;
    cb[t] = cand[colChunk * 64 + t];
    __syncthreads();

    int r = rowChunk * 64 + t;
    unsigned long long m = 0ull;
    if (r < KNMS) {
        float4 R = cand[r];
        float areaR = (R.z - R.x) * (R.w - R.y);
        #pragma unroll 8
        for (int c = 0; c < 64; ++c) {
            int col = colChunk * 64 + c;
            if (col < KNMS && col > r) {
                float4 C = cb[c];
                float areaC = (C.z - C.x) * (C.w - C.y);
                float lx = fmaxf(R.x, C.x), ly = fmaxf(R.y, C.y);
                float rx = fminf(R.z, C.z), ry = fminf(R.w, C.w);
                float iw = fmaxf(rx - lx, 0.0f), ih = fmaxf(ry - ly, 0.0f);
                float inter = iw * ih;
                float iou = inter / (areaR + areaC - inter);
                if (iou > 0.7f) m |= (1ull << c);
            }
        }
    }
    // transposed store: maskT[word][row]; coalesced over t (consecutive rows)
    __builtin_nontemporal_store((unsigned int)m,
        &maskT[(size_t)(2 * colChunk + 0) * RPAD + r]);
    __builtin_nontemporal_store((unsigned int)(m >> 32),
        &maskT[(size_t)(2 * colChunk + 1) * RPAD + r]);
    if (rowChunk == colChunk)
        __builtin_nontemporal_store(m, &diagw[r]);
}

// Serial NMS, single wave, no LDS staging for the per-lane words:
//  - Wv: 16 coalesced global_load_dwordx4 per block, straight to VGPRs,
//    prefetched 2 blocks ahead; one counted vmcnt(17) per block.
//  - diag: 512B/block via ONE global_load_lds into a 2-slot LDS ring, read
//    back as uniform-address ds_read_b128 broadcasts (4 per octant, <=8
//    outstanding -- inside gfx9's 4-bit lgkmcnt range), octant-prefetched.
//  - chain: 5 VALU/row (bfe, add, 3x v_and_or_b32), remv split into 2
//    accumulators to halve the OR-chain latency.
__global__ __launch_bounds__(64) void k_nms(
    const unsigned int* __restrict__ maskT,
    const unsigned long long* __restrict__ diagw,
    float* __restrict__ keep_out)
{
    __shared__ alignas(16) unsigned long long Dlds[2][64];   // 2 x 512B diag ring
    const int lane = threadIdx.x;
    const unsigned int* wp = maskT + (size_t)lane * RPAD;

    uint4 w0[16], w1[16];
    unsigned int remv0 = 0u, remv1 = 0u;

#define STAGE(b, p, wbuf) do {                                                 \
        if (lane < 32)                                                         \
            __builtin_amdgcn_global_load_lds(                                  \
                (const unsigned int*)((const char*)diagw + (size_t)(b) * 512 + lane * 16), \
                (unsigned int*)&Dlds[p][0], 16, 0, 0);                         \
        const uint4* q_ = (const uint4*)(wp + (b) * 64);                       \
        _Pragma("unroll")                                                      \
        for (int t_ = 0; t_ < 16; ++t_) (wbuf)[t_] = q_[t_];                   \
    } while (0)

#define RDOCT(dst, p, o) do {                                                  \
        const uint4* dp_ = (const uint4*)&Dlds[p][(o) * 8];                    \
        (dst)[0] = dp_[0]; (dst)[1] = dp_[1];                                  \
        (dst)[2] = dp_[2]; (dst)[3] = dp_[3];                                  \
    } while (0)

#define WCOMP(wbuf, r) (((r) & 3) == 0 ? (wbuf)[(r) >> 2].x :                  \
                        ((r) & 3) == 1 ? (wbuf)[(r) >> 2].y :                  \
                        ((r) & 3) == 2 ? (wbuf)[(r) >> 2].z : (wbuf)[(r) >> 2].w)

#define ROW(r, ob_, wbuf) do {                                                 \
        unsigned int t_ = ((r) < 32) ? ((cur_lo >> (r)) & 1u)                  \
                                     : ((cur_hi >> ((r) - 32)) & 1u);          \
        unsigned int sel_ = t_ - 1u;                                           \
        unsigned int dl_ = ((r) & 1) ? (ob_)[((r) & 7) >> 1].z                 \
                                     : (ob_)[((r) & 7) >> 1].x;                \
        unsigned int dh_ = ((r) & 1) ? (ob_)[((r) & 7) >> 1].w                 \
                                     : (ob_)[((r) & 7) >> 1].y;                \
        unsigned int wv_ = WCOMP(wbuf, r);                                     \
        cur_lo |= dl_ & sel_;                                                  \
        cur_hi |= dh_ & sel_;                                                  \
        if ((r) & 1) remv1 |= wv_ & sel_; else remv0 |= wv_ & sel_;            \
    } while (0)

#define OCT8(base, ob_, wbuf) do {                                             \
        ROW((base) + 0, ob_, wbuf); ROW((base) + 1, ob_, wbuf);                \
        ROW((base) + 2, ob_, wbuf); ROW((base) + 3, ob_, wbuf);                \
        ROW((base) + 4, ob_, wbuf); ROW((base) + 5, ob_, wbuf);                \
        ROW((base) + 6, ob_, wbuf); ROW((base) + 7, ob_, wbuf);                \
    } while (0)

#define BLK(b, p, wbuf, VMC, DO_STAGE) do {                                    \
        asm volatile("s_waitcnt vmcnt(" #VMC ")" ::: "memory");                \
        __builtin_amdgcn_sched_barrier(0);                                     \
        unsigned int remvm_ = remv0 | remv1;                                   \
        unsigned int cur_lo = (unsigned int)__builtin_amdgcn_readlane((int)remvm_, 2 * (b));     \
        unsigned int cur_hi = (unsigned int)__builtin_amdgcn_readlane((int)remvm_, 2 * (b) + 1); \
        uint4 oa[4], ob2[4], oc[4];                                            \
        RDOCT(oa, p, 0); RDOCT(ob2, p, 1);                                     \
        RDOCT(oc,  p, 2); OCT8(0,  oa,  wbuf);                                 \
        RDOCT(oa,  p, 3); OCT8(8,  ob2, wbuf);                                 \
        RDOCT(ob2, p, 4); OCT8(16, oc,  wbuf);                                 \
        RDOCT(oc,  p, 5); OCT8(24, oa,  wbuf);                                 \
        RDOCT(oa,  p, 6); OCT8(32, ob2, wbuf);                                 \
        RDOCT(ob2, p, 7); OCT8(40, oc,  wbuf);                                 \
        OCT8(48, oa,  wbuf);                                                   \
        OCT8(56, ob2, wbuf);                                                   \
        {                                                                      \
            int row_ = (b) * 64 + lane;                                        \
            unsigned int half_ = (lane < 32) ? cur_lo : cur_hi;                \
            float kf_ = ((half_ >> (lane & 31)) & 1u) ? 0.0f : 1.0f;           \
            if (row_ < KNMS) keep_out[row_] = kf_;                             \
        }                                                                      \
        if (DO_STAGE) STAGE((b) + 2, p, wbuf);                                 \
    } while (0)

    STAGE(0, 0, w0);
    STAGE(1, 1, w1);

    for (int bb = 0; bb < 30; bb += 2) {
        BLK(bb,     0, w0, 17, true);
        BLK(bb + 1, 1, w1, 17, true);
    }
    BLK(30, 0, w0, 17, false);
    BLK(31, 1, w1, 0,  false);

#undef BLK
#undef OCT8
#undef ROW
#undef WCOMP
#undef RDOCT
#undef STAGE
}

extern "C" void kernel_launch(void* const* d_in, const int* in_sizes, int n_in,
                              void* d_out, int out_size, void* d_ws, size_t ws_size,
                              hipStream_t stream) {
    const float* true_bx = (const float*)d_in[2];
    const float* deltas  = (const float*)d_in[3];
    const float* scores  = (const float*)d_in[4];
    float* out = (float*)d_out;

    char* ws = (char*)d_ws;
    unsigned long long* keys  = (unsigned long long*)(ws + 0);
    unsigned int*       hist  = (unsigned int*)(ws + 720000);
    unsigned long long* diagw = (unsigned long long*)(ws + 720000);  // aliases hist (ordered)
    unsigned int*       ctr   = (unsigned int*)(ws + 736384);
    unsigned long long* buf   = (unsigned long long*)(ws + 736400);
    float4*             cand  = (float4*)(ws + 769168);
    unsigned int*       maskT = (unsigned int*)(ws + 801936);

    hipLaunchKernelGGL(k_zero, dim3(16), dim3(256), 0, stream, hist, ctr);
    hipLaunchKernelGGL(k_prep, dim3((NA + 255) / 256), dim3(256), 0, stream,
                       true_bx, deltas, scores, out, keys, hist);
    hipLaunchKernelGGL(k_compact, dim3((NA + 255) / 256), dim3(256), 0, stream,
                       scores, keys, hist, ctr, buf);
    hipLaunchKernelGGL(k_rank, dim3(CMAX / 256), dim3(256), 0, stream, ctr, buf, out, cand);
    hipLaunchKernelGGL(k_mask, dim3(32, 32), dim3(64), 0, stream, cand, maskT, diagw);
    hipLaunchKernelGGL(k_nms, dim3(1), dim3(64), 0, stream, maskT, diagw,
                       out + (size_t)NA * 9);
}